// Round 8
// baseline (467.917 us; speedup 1.0000x reference)
//
#include <hip/hip_runtime.h>
#include <stdint.h>

// Problem constants (fixed by the reference)
#define NN 50000
#define EE 800000
#define FF 256
#define HH 256
#define LL 128
#define SBLK 1024   // bnstats stage-A blocks
#define CSRCAP 1200128  // EE + 8*NN + pad; rows 8-aligned, zero-padded
#define SCAP 4096   // staged csr entries per spmm block (16 KB LDS; 64-row spans avg ~1280)

typedef __bf16 bf16x8 __attribute__((ext_vector_type(8)));
typedef float  f32x4  __attribute__((ext_vector_type(4)));
typedef unsigned int u32x2 __attribute__((ext_vector_type(2)));
typedef unsigned int u32x4 __attribute__((ext_vector_type(4)));

typedef __attribute__((address_space(1))) unsigned int uint_as1;
typedef __attribute__((address_space(3))) unsigned int uint_as3;

__device__ __forceinline__ unsigned short f2bf(float f) {
  union { float f; unsigned int u; } v; v.f = f;
  unsigned int u = v.u;
  u += 0x7FFFu + ((u >> 16) & 1u);   // RTNE (finite inputs only)
  return (unsigned short)(u >> 16);
}

__device__ __forceinline__ float bf2f(unsigned short u) {
  union { unsigned int u; float f; } v;
  v.u = ((unsigned int)u) << 16;
  return v.f;
}

__device__ __forceinline__ f32x4 bf4_to_f32(ushort4 u) {
  f32x4 r;
  r.x = bf2f(u.x); r.y = bf2f(u.y); r.z = bf2f(u.z); r.w = bf2f(u.w);
  return r;
}

__device__ __forceinline__ void gload_lds16(const void* g, void* l) {
  __builtin_amdgcn_global_load_lds((const uint_as1*)g, (uint_as3*)l, 16, 0, 0);
}

// ---------------- fused setup: edge histogram + feature cast + weight transposes ----
// grid: [0,3125) hist | [3125,15625) features | [15625,15665) weight 64x64 tiles
// hist first so its latency-bound atomic waves overlap the streaming casts.
__global__ __launch_bounds__(256) void k_setup(const int* __restrict__ erows,
                                               int* __restrict__ cnt,
                                               const float* __restrict__ features,
                                               unsigned short* __restrict__ Xb,
                                               const float* __restrict__ W1,
                                               unsigned short* __restrict__ W1t,
                                               const float* __restrict__ W2,
                                               unsigned short* __restrict__ W2t,
                                               const float* __restrict__ Wf,
                                               unsigned short* __restrict__ Wft) {
  __shared__ float tl[64 * 65];
  int b = blockIdx.x, t = threadIdx.x;
  if (b < 3125) {
    int i = b * 256 + t;
    if (i < EE) atomicAdd(&cnt[erows[i]], 1);
  } else if (b < 15625) {
    int i = (b - 3125) * 256 + t;  // n4 = 3,200,000 exactly
    f32x4 x = ((const f32x4*)features)[i];
    ushort4 o;
    o.x = f2bf(x.x); o.y = f2bf(x.y); o.z = f2bf(x.z); o.w = f2bf(x.w);
    ((ushort4*)Xb)[i] = o;
  } else {
    int tt = b - 15625;
    const float* in;
    unsigned short* out;
    int Nin, k0, n0;
    if (tt < 16) {
      in = W1; out = W1t; Nin = HH;
      k0 = (tt >> 2) * 64; n0 = (tt & 3) * 64;
    } else if (tt < 32) {
      in = W2; out = W2t; Nin = HH;
      tt -= 16; k0 = (tt >> 2) * 64; n0 = (tt & 3) * 64;
    } else {
      in = Wf; out = Wft; Nin = LL;
      tt -= 32; k0 = (tt >> 1) * 64; n0 = (tt & 1) * 64;
    }
#pragma unroll
    for (int j = 0; j < 16; ++j) {
      int idx = j * 256 + t;
      int r = idx >> 6, c = idx & 63;
      tl[r * 65 + c] = in[(size_t)(k0 + r) * Nin + n0 + c];
    }
    __syncthreads();
#pragma unroll
    for (int j = 0; j < 16; ++j) {
      int idx = j * 256 + t;
      int r = idx >> 6, c = idx & 63;
      out[(size_t)(n0 + r) * HH + k0 + c] = f2bf(tl[c * 65 + r]);
    }
  }
}

// Unordered exclusive allocation, row starts 8-ALIGNED (for spmm oct loops).
// Wave-scan of aligned counts + one global atomic per wave -> any aligned
// 64-row chunk (one wave group) has a CONTIGUOUS ascending csr span (spmm LDS
// staging relies on this). Pad slots stay 0 in csr (pre-zeroed): val=0, harmless.
__global__ __launch_bounds__(256) void k_alloc(const int* __restrict__ cnt,
                                               int* __restrict__ cursor,
                                               int* __restrict__ total, int n) {
  int i = blockIdx.x * 256 + threadIdx.x;
  int lane = threadIdx.x & 63;
  int c = (i < n) ? ((cnt[i] + 7) & ~7) : 0;
  int incl = c;
#pragma unroll
  for (int off = 1; off < 64; off <<= 1) {
    int v = __shfl_up(incl, off, 64);
    if (lane >= off) incl += v;
  }
  int excl = incl - c;
  int wtot = __shfl(incl, 63, 64);
  int base = 0;
  if (lane == 0) base = atomicAdd(total, wtot);
  base = __shfl(base, 0, 64);
  if (i < n) cursor[i] = base + excl;
}

// ---------------- fused layer-1 GEMM + CSR fill ----------------
// 1564 blocks: even = gemm tile (gb = b>>1, 782 tiles of 128x128), odd = fill
// (grid-stride, 4 independent atomic+scatter per thread). Fill's atomic latency
// hides under gemm's MFMA work (separate pipes co-schedule).
// CSR entry packed to 4B: (col << 16) | bf16(val).
// C is written in XCD-SLICED layout: C[slice=cn>>5][row][cn&31], slice region
// = NN*32 shorts (3.2 MB, contiguous) so each XCD's spmm gather set fits its 4MB L2.
__global__ __launch_bounds__(256, 3) void k_l1(const unsigned short* __restrict__ A,
                                               const unsigned short* __restrict__ Bt,
                                               const float* __restrict__ bias,
                                               unsigned short* __restrict__ C,
                                               int M, int K, int Nn,
                                               const int* __restrict__ rows,
                                               const int* __restrict__ cols,
                                               const float* __restrict__ vals,
                                               int* __restrict__ cursor,
                                               unsigned int* __restrict__ csr, int E) {
  __shared__ unsigned short lA[128 * 64];  // 16 KB
  __shared__ unsigned short lB[128 * 64];  // 16 KB
  const int b = blockIdx.x;
  const int tid = threadIdx.x;
  if (b & 1) {
    for (int i = (b >> 1) * 256 + tid; i < E; i += 782 * 256) {
      int p = atomicAdd(&cursor[rows[i]], 1);
      csr[p] = ((unsigned int)cols[i] << 16) | (unsigned int)f2bf(vals[i]);
    }
    return;
  }
  const int gb = b >> 1;
  const int m0 = (gb % 391) * 128, n0 = (gb / 391) * 128;
  const int wave = tid >> 6, lane = tid & 63;
  const int wm = (wave >> 1) * 64, wn = (wave & 1) * 64;
  const int lhi = lane >> 4, llo = lane & 15;
  const int srow = lane >> 3;
  const int scol = (lane & 7) * 8;
  const unsigned short *pA[4], *pB[4];
#pragma unroll
  for (int j = 0; j < 4; ++j) {
    int base = (wave * 4 + j) * 8 + srow;
    int ar = m0 + base;
    ar = ar < M ? ar : 0;
    pA[j] = A + (size_t)ar * K + scol;
    pB[j] = Bt + (size_t)(n0 + base) * K + scol;
  }
  f32x4 zero = {0.f, 0.f, 0.f, 0.f};
  f32x4 acc[4][4];
#pragma unroll
  for (int i = 0; i < 4; ++i)
#pragma unroll
    for (int j = 0; j < 4; ++j) acc[i][j] = zero;
  for (int k0 = 0; k0 < K; k0 += 64) {
#pragma unroll
    for (int j = 0; j < 4; ++j) {
      gload_lds16(pA[j] + k0, lA + (wave * 4 + j) * 8 * 64);
      gload_lds16(pB[j] + k0, lB + (wave * 4 + j) * 8 * 64);
    }
    __syncthreads();
    bf16x8 af[2][4], bfv[2][4];
#pragma unroll
    for (int ks = 0; ks < 2; ++ks) {
#pragma unroll
      for (int mt = 0; mt < 4; ++mt)
        af[ks][mt] = *(const bf16x8*)(lA + (wm + mt * 16 + llo) * 64 + ks * 32 + lhi * 8);
#pragma unroll
      for (int nt = 0; nt < 4; ++nt)
        bfv[ks][nt] = *(const bf16x8*)(lB + (wn + nt * 16 + llo) * 64 + ks * 32 + lhi * 8);
    }
#pragma unroll
    for (int ks = 0; ks < 2; ++ks)
#pragma unroll
      for (int mt = 0; mt < 4; ++mt)
#pragma unroll
        for (int nt = 0; nt < 4; ++nt)
          acc[mt][nt] = __builtin_amdgcn_mfma_f32_16x16x32_bf16(af[ks][mt], bfv[ks][nt], acc[mt][nt], 0, 0, 0);
    __syncthreads();
  }
#pragma unroll
  for (int nt = 0; nt < 4; ++nt) {
    int cn = n0 + wn + nt * 16 + llo;
    float bv = bias[cn];
    unsigned short* Cs = C + (size_t)(cn >> 5) * ((size_t)NN * 32) + (cn & 31);
#pragma unroll
    for (int mt = 0; mt < 4; ++mt) {
      int cm0 = m0 + wm + mt * 16 + lhi * 4;
#pragma unroll
      for (int r = 0; r < 4; ++r) {
        int cm = cm0 + r;
        if (cm < M) Cs[(size_t)cm * 32] = f2bf(acc[mt][nt][r] + bv);
      }
    }
  }
}

// ---------------- SpMM, XCD-column-sliced, LDS-staged csr, 2-row interleave ------
// X is SLICED: X[slice][row][32 cols], 3.2 MB contiguous -> L2-resident per XCD
// (slice = blockIdx&7 -> XCD; confirmed r2-r7: FETCH ~31 MB = X + L3-served csr).
// r7 state: LDS staging fixed the serial csr feed (87->66us) but VALUBusy 40% ->
// still short of the ~170 outstanding 64B gathers/CU needed to saturate per-XCD
// L2 (each wave held ~16). THIS ROUND: each 8-lane group owns TWO rows (64-row
// chunks, wave covers 16 rows); the crunch interleaves both rows' octs with all
// 16 gathers issued before the FMAs -> 2x independent chains per wave.
// Row math (r6 lesson): start = endp-cnt (8-aligned); iterate to start+align8(cnt);
// tail pads pre-zeroed (val=0, harmless). 64-row chunks = exactly one k_alloc
// wave group -> span contiguous ascending. Global fallback keeps correctness
// unconditional for spans > SCAP (statistically impossible: ~1280 +/- 36 vs 4096).
__global__ __launch_bounds__(256) void k_spmm(const unsigned short* __restrict__ X,
                                              const int* __restrict__ endp,
                                              const int* __restrict__ cnt,
                                              const unsigned int* __restrict__ csr,
                                              unsigned short* __restrict__ Y, int n) {
  __shared__ unsigned int lcsr[SCAP];
  const int slice = blockIdx.x & 7;
  const int r0 = (blockIdx.x >> 3) * 64;
  const int tid = threadIdx.x;
  const int wave = tid >> 6, lane = tid & 63;
  const int grp = lane >> 3;           // group 0..7 within wave
  const int cl = lane & 7;             // column quad within slice
  const unsigned short* Xs = X + (size_t)slice * ((size_t)NN * 32) + cl * 4;

  // block csr span: rows r0..rlast contiguous ascending (one k_alloc wave group)
  const int rlast = (r0 + 63 < n) ? (r0 + 63) : (n - 1);
  const int s0 = endp[r0] - cnt[r0];                 // row r0 start (8-aligned)
  const int clast = cnt[rlast];
  const int send = (endp[rlast] - clast) + ((clast + 7) & ~7);  // aligned end
  const int len0 = send - s0;                        // multiple of 8
  const int len = len0 < SCAP ? len0 : SCAP;
  for (int j = tid * 4; j < len; j += 1024)
    *(u32x4*)(lcsr + j) = __builtin_nontemporal_load((const u32x4*)(csr + s0 + j));
  __syncthreads();

  const int rowA = r0 + wave * 16 + grp;
  const int rowB = rowA + 8;
  int qA = s0, eA = s0, qB = s0, eB = s0;
  if (rowA < n) {
    const int c = cnt[rowA];
    qA = endp[rowA] - c;
    eA = qA + ((c + 7) & ~7);
  }
  if (rowB < n) {
    const int c = cnt[rowB];
    qB = endp[rowB] - c;
    eB = qB + ((c + 7) & ~7);
  }

  f32x4 aA0 = {0.f, 0.f, 0.f, 0.f}, aA1 = aA0, aA2 = aA0, aA3 = aA0;
  f32x4 aB0 = aA0, aB1 = aA0, aB2 = aA0, aB3 = aA0;

  auto gat = [&](unsigned int c) -> ushort4 {
    return *(const ushort4*)(Xs + ((size_t)(c >> 16) << 5));
  };
  auto octA = [&](u32x4 ca, u32x4 cb) {
    const ushort4 x0 = gat(ca.x), x1 = gat(ca.y), x2 = gat(ca.z), x3 = gat(ca.w);
    const ushort4 x4 = gat(cb.x), x5 = gat(cb.y), x6 = gat(cb.z), x7 = gat(cb.w);
    aA0 += bf2f((unsigned short)ca.x) * bf4_to_f32(x0);
    aA1 += bf2f((unsigned short)ca.y) * bf4_to_f32(x1);
    aA2 += bf2f((unsigned short)ca.z) * bf4_to_f32(x2);
    aA3 += bf2f((unsigned short)ca.w) * bf4_to_f32(x3);
    aA0 += bf2f((unsigned short)cb.x) * bf4_to_f32(x4);
    aA1 += bf2f((unsigned short)cb.y) * bf4_to_f32(x5);
    aA2 += bf2f((unsigned short)cb.z) * bf4_to_f32(x6);
    aA3 += bf2f((unsigned short)cb.w) * bf4_to_f32(x7);
  };
  auto octB = [&](u32x4 ca, u32x4 cb) {
    const ushort4 x0 = gat(ca.x), x1 = gat(ca.y), x2 = gat(ca.z), x3 = gat(ca.w);
    const ushort4 x4 = gat(cb.x), x5 = gat(cb.y), x6 = gat(cb.z), x7 = gat(cb.w);
    aB0 += bf2f((unsigned short)ca.x) * bf4_to_f32(x0);
    aB1 += bf2f((unsigned short)ca.y) * bf4_to_f32(x1);
    aB2 += bf2f((unsigned short)ca.z) * bf4_to_f32(x2);
    aB3 += bf2f((unsigned short)ca.w) * bf4_to_f32(x3);
    aB0 += bf2f((unsigned short)cb.x) * bf4_to_f32(x4);
    aB1 += bf2f((unsigned short)cb.y) * bf4_to_f32(x5);
    aB2 += bf2f((unsigned short)cb.z) * bf4_to_f32(x6);
    aB3 += bf2f((unsigned short)cb.w) * bf4_to_f32(x7);
  };

  if (len0 <= len) {
    // LDS path (always, in practice): 2 rows interleaved, 16 gathers in flight
    const unsigned int* lpA = lcsr + (qA - s0);
    const unsigned int* lpB = lcsr + (qB - s0);
    while (qA < eA && qB < eB) {
      u32x4 ca = *(const u32x4*)(lpA), cb = *(const u32x4*)(lpA + 4);
      u32x4 cc = *(const u32x4*)(lpB), cd = *(const u32x4*)(lpB + 4);
      octA(ca, cb);
      octB(cc, cd);
      qA += 8; lpA += 8; qB += 8; lpB += 8;
    }
    for (; qA < eA; qA += 8, lpA += 8)
      octA(*(const u32x4*)(lpA), *(const u32x4*)(lpA + 4));
    for (; qB < eB; qB += 8, lpB += 8)
      octB(*(const u32x4*)(lpB), *(const u32x4*)(lpB + 4));
  } else {
    // cold fallback: direct global
    for (; qA < eA; qA += 8)
      octA(__builtin_nontemporal_load((const u32x4*)(csr + qA)),
           __builtin_nontemporal_load((const u32x4*)(csr + qA + 4)));
    for (; qB < eB; qB += 8)
      octB(__builtin_nontemporal_load((const u32x4*)(csr + qB)),
           __builtin_nontemporal_load((const u32x4*)(csr + qB + 4)));
  }

  if (rowA < n) {
    const f32x4 a = (aA0 + aA1) + (aA2 + aA3);
    u32x2 o;
    o.x = ((unsigned int)f2bf(a.y) << 16) | (unsigned int)f2bf(a.x);
    o.y = ((unsigned int)f2bf(a.w) << 16) | (unsigned int)f2bf(a.z);
    __builtin_nontemporal_store(o, (u32x2*)(Y + (size_t)rowA * HH + slice * 32 + cl * 4));
  }
  if (rowB < n) {
    const f32x4 a = (aB0 + aB1) + (aB2 + aB3);
    u32x2 o;
    o.x = ((unsigned int)f2bf(a.y) << 16) | (unsigned int)f2bf(a.x);
    o.y = ((unsigned int)f2bf(a.w) << 16) | (unsigned int)f2bf(a.z);
    __builtin_nontemporal_store(o, (u32x2*)(Y + (size_t)rowB * HH + slice * 32 + cl * 4));
  }
}

// ---------------- BatchNorm stats, two-stage (atomic-light) ----------------
__global__ __launch_bounds__(256) void k_bnstats(const unsigned short* __restrict__ X,
                                                 float* __restrict__ part, int n) {
  __shared__ float red[4][64][9];
  const int w = threadIdx.x >> 6, l = threadIdx.x & 63;
  f32x4 s = {0.f, 0.f, 0.f, 0.f}, s2 = {0.f, 0.f, 0.f, 0.f};
  for (int r = blockIdx.x * 4 + w; r < n; r += gridDim.x * 4) {
    f32x4 v = bf4_to_f32(((const ushort4*)(X + (size_t)r * HH))[l]);
    s += v;
    s2 += v * v;
  }
#pragma unroll
  for (int j = 0; j < 4; ++j) { red[w][l][j] = s[j]; red[w][l][4 + j] = s2[j]; }
  __syncthreads();
  if (threadIdx.x < 64) {
    int ll = threadIdx.x;
#pragma unroll
    for (int j = 0; j < 8; ++j) {
      float v = red[0][ll][j] + red[1][ll][j] + red[2][ll][j] + red[3][ll][j];
      int c = ll * 4 + (j & 3);
      part[((j < 4) ? 0 : (SBLK * 256)) + blockIdx.x * 256 + c] = v;
    }
  }
}

// Stage B: 16 blocks = 8 chunks x 2 stats; 128 partials each, 8-deep atomicAdd/col.
__global__ __launch_bounds__(256) void k_bnred(const float* __restrict__ part,
                                               float* __restrict__ sums) {
  int c = threadIdx.x;
  int stat = blockIdx.x >> 3, chunk = blockIdx.x & 7;
  const float* p = part + stat * (SBLK * 256) + chunk * 128 * 256;
  float s0 = 0.f, s1 = 0.f, s2 = 0.f, s3 = 0.f;
  for (int b = 0; b < 128; b += 4) {
    s0 += p[(b + 0) * 256 + c];
    s1 += p[(b + 1) * 256 + c];
    s2 += p[(b + 2) * 256 + c];
    s3 += p[(b + 3) * 256 + c];
  }
  atomicAdd(&sums[stat * HH + c], (s0 + s1) + (s2 + s3));
}

// y = bf16(relu(x*scale + shift)); scale/shift computed per-block from raw sums
__global__ __launch_bounds__(256) void k_bnrc(const unsigned short* __restrict__ X,
                                              const float* __restrict__ sums,
                                              const float* __restrict__ g,
                                              const float* __restrict__ be,
                                              unsigned short* __restrict__ out, int n4) {
  __shared__ float sc[HH], sh[HH];
  int t = threadIdx.x;
  {
    float inv = 1.f / (float)NN;
    float mean = sums[t] * inv;
    float var = sums[HH + t] * inv - mean * mean;
    float s = g[t] * rsqrtf(var + 1e-5f);
    sc[t] = s;
    sh[t] = be[t] - mean * s;
  }
  __syncthreads();
  for (int i = blockIdx.x * 256 + t; i < n4; i += gridDim.x * 256) {
    f32x4 x = bf4_to_f32(((const ushort4*)X)[i]);
    int c0 = (i * 4) & (HH - 1);
    ushort4 o;
    o.x = f2bf(fmaxf(x.x * sc[c0 + 0] + sh[c0 + 0], 0.f));
    o.y = f2bf(fmaxf(x.y * sc[c0 + 1] + sh[c0 + 1], 0.f));
    o.z = f2bf(fmaxf(x.z * sc[c0 + 2] + sh[c0 + 2], 0.f));
    o.w = f2bf(fmaxf(x.w * sc[c0 + 3] + sh[c0 + 3], 0.f));
    ((ushort4*)out)[i] = o;
  }
}

// Layer-2 BN apply, packed for the head: out[r] = bf16(relu(BN(X[idx[r]]))).
__global__ __launch_bounds__(256) void k_bnrc_pack(const unsigned short* __restrict__ X,
                                                   const float* __restrict__ sums,
                                                   const float* __restrict__ g,
                                                   const float* __restrict__ be,
                                                   const int* __restrict__ idx,
                                                   unsigned short* __restrict__ out) {
  __shared__ float sc[HH], sh[HH];
  int t = threadIdx.x;
  {
    float inv = 1.f / (float)NN;
    float mean = sums[t] * inv;
    float var = sums[HH + t] * inv - mean * mean;
    float s = g[t] * rsqrtf(var + 1e-5f);
    sc[t] = s;
    sh[t] = be[t] - mean * s;
  }
  __syncthreads();
  int i = blockIdx.x * 256 + t;
  int orow = i >> 6;           // wave-uniform
  int c0 = (i & 63) * 4;
  int irow = idx[orow];
  f32x4 x = bf4_to_f32(*(const ushort4*)(X + (size_t)irow * HH + c0));
  ushort4 o;
  o.x = f2bf(fmaxf(x.x * sc[c0 + 0] + sh[c0 + 0], 0.f));
  o.y = f2bf(fmaxf(x.y * sc[c0 + 1] + sh[c0 + 1], 0.f));
  o.z = f2bf(fmaxf(x.z * sc[c0 + 2] + sh[c0 + 2], 0.f));
  o.w = f2bf(fmaxf(x.w * sc[c0 + 3] + sh[c0 + 3], 0.f));
  ((ushort4*)out)[i] = o;
}

// ---------------- GEMM: C(MxNn) = A(MxK,bf16) * Bt(NnxK,bf16)^T + bias ----------------
// 128x128 tile, BK=64, 3 blocks/CU. OUTB=1: bf16 out in XCD-SLICED layout
// [slice=cn>>5][row][cn&31] (feeds k_spmm); 0: fp32 out, row-major.
template <int OUTB>
__global__ __launch_bounds__(256, 3) void k_gemm(const unsigned short* __restrict__ A,
                                                 const unsigned short* __restrict__ Bt,
                                                 const float* __restrict__ bias,
                                                 void* __restrict__ Cv,
                                                 int M, int K, int Nn) {
  __shared__ unsigned short lA[128 * 64];
  __shared__ unsigned short lB[128 * 64];
  const int tid = threadIdx.x;
  const int wave = tid >> 6, lane = tid & 63;
  const int m0 = blockIdx.x * 128, n0 = blockIdx.y * 128;
  const int wm = (wave >> 1) * 64, wn = (wave & 1) * 64;
  const int lhi = lane >> 4, llo = lane & 15;
  const int srow = lane >> 3;
  const int scol = (lane & 7) * 8;
  const unsigned short *pA[4], *pB[4];
#pragma unroll
  for (int j = 0; j < 4; ++j) {
    int base = (wave * 4 + j) * 8 + srow;
    int ar = m0 + base;
    ar = ar < M ? ar : 0;
    pA[j] = A + (size_t)ar * K + scol;
    pB[j] = Bt + (size_t)(n0 + base) * K + scol;
  }
  f32x4 zero = {0.f, 0.f, 0.f, 0.f};
  f32x4 acc[4][4];
#pragma unroll
  for (int i = 0; i < 4; ++i)
#pragma unroll
    for (int j = 0; j < 4; ++j) acc[i][j] = zero;
  for (int k0 = 0; k0 < K; k0 += 64) {
#pragma unroll
    for (int j = 0; j < 4; ++j) {
      gload_lds16(pA[j] + k0, lA + (wave * 4 + j) * 8 * 64);
      gload_lds16(pB[j] + k0, lB + (wave * 4 + j) * 8 * 64);
    }
    __syncthreads();
    bf16x8 af[2][4], bfv[2][4];
#pragma unroll
    for (int ks = 0; ks < 2; ++ks) {
#pragma unroll
      for (int mt = 0; mt < 4; ++mt)
        af[ks][mt] = *(const bf16x8*)(lA + (wm + mt * 16 + llo) * 64 + ks * 32 + lhi * 8);
#pragma unroll
      for (int nt = 0; nt < 4; ++nt)
        bfv[ks][nt] = *(const bf16x8*)(lB + (wn + nt * 16 + llo) * 64 + ks * 32 + lhi * 8);
    }
#pragma unroll
    for (int ks = 0; ks < 2; ++ks)
#pragma unroll
      for (int mt = 0; mt < 4; ++mt)
#pragma unroll
        for (int nt = 0; nt < 4; ++nt)
          acc[mt][nt] = __builtin_amdgcn_mfma_f32_16x16x32_bf16(af[ks][mt], bfv[ks][nt], acc[mt][nt], 0, 0, 0);
    __syncthreads();
  }
#pragma unroll
  for (int nt = 0; nt < 4; ++nt) {
    int cn = n0 + wn + nt * 16 + llo;
    float bv = bias ? bias[cn] : 0.f;
#pragma unroll
    for (int mt = 0; mt < 4; ++mt) {
      int cm0 = m0 + wm + mt * 16 + lhi * 4;
#pragma unroll
      for (int r = 0; r < 4; ++r) {
        int cm = cm0 + r;
        if (cm < M) {
          float v = acc[mt][nt][r] + bv;
          if (OUTB)
            ((unsigned short*)Cv)[(size_t)(cn >> 5) * ((size_t)NN * 32) +
                                  (size_t)cm * 32 + (cn & 31)] = f2bf(v);
          else
            ((float*)Cv)[(size_t)cm * Nn + cn] = v;
        }
      }
    }
  }
}

extern "C" void kernel_launch(void* const* d_in, const int* in_sizes, int n_in,
                              void* d_out, int out_size, void* d_ws, size_t ws_size,
                              hipStream_t stream) {
  const float* features = (const float*)d_in[0];
  const float* edge_vals = (const float*)d_in[1];
  const float* W1 = (const float*)d_in[2];
  const float* db1 = (const float*)d_in[3];
  // d_in[4] = b1  — annihilated by training-mode BN
  const float* g1 = (const float*)d_in[5];
  const float* be1 = (const float*)d_in[6];
  const float* W2 = (const float*)d_in[7];
  // d_in[8] = b2  — annihilated by BN
  const float* g2 = (const float*)d_in[9];
  const float* be2 = (const float*)d_in[10];
  const float* Wf = (const float*)d_in[11];
  const float* bfb = (const float*)d_in[12];
  const int* erows = (const int*)d_in[13];
  const int* ecols = (const int*)d_in[14];
  const int* idx = (const int*)d_in[15];
  const int M3 = in_sizes[15];
  (void)n_in; (void)out_size; (void)ws_size;

  char* ws = (char*)d_ws;
  size_t off = 0;
  auto alloc = [&](size_t bytes) -> void* {
    void* p = (void*)(ws + off);
    off += (bytes + 255) & ~(size_t)255;
    return p;
  };
  unsigned short* Xb = (unsigned short*)alloc((size_t)NN * HH * 2);
  unsigned short* Ab = (unsigned short*)alloc((size_t)NN * HH * 2);
  unsigned short* Yb = (unsigned short*)alloc((size_t)NN * HH * 2);
  unsigned short* Pb = (unsigned short*)alloc((size_t)25000 * HH * 2);
  unsigned short* W1t = (unsigned short*)alloc((size_t)FF * HH * 2);
  unsigned short* W2t = (unsigned short*)alloc((size_t)HH * HH * 2);
  unsigned short* Wft = (unsigned short*)alloc((size_t)HH * LL * 2);
  int* cursor = (int*)alloc((size_t)NN * 4);
  int* cnt = (int*)alloc((size_t)NN * 4);
  unsigned int* csr = (unsigned int*)alloc((size_t)CSRCAP * 4);
  float* part = (float*)alloc((size_t)2 * SBLK * 256 * 4);
  float* stats = (float*)alloc(4 * HH * 4 + 256);
  float* sums1 = stats;
  float* sums2 = stats + 2 * HH;
  int* total = (int*)(stats + 4 * HH);

  hipMemsetAsync(cnt, 0, (size_t)NN * 4, stream);
  hipMemsetAsync(csr, 0, (size_t)CSRCAP * 4, stream);  // zero pads: val=0 entries
  hipMemsetAsync(stats, 0, 4 * HH * 4 + 256, stream);

  // setup: hist + feature cast + weight transposes (one launch, hist first)
  k_setup<<<15665, 256, 0, stream>>>(erows, cnt, features, Xb, W1, W1t, W2, W2t, Wf, Wft);
  k_alloc<<<(NN + 255) / 256, 256, 0, stream>>>(cnt, cursor, total, NN);

  // layer 1: gemm fused with CSR fill (independent work, co-scheduled)
  k_l1<<<1564, 256, 0, stream>>>(Xb, W1t, db1, Ab, NN, FF, HH,
                                 erows, ecols, edge_vals, cursor, csr, EE);
  // after k_l1: cursor[row] == row start + cnt[row]
  // sliced spmm: 8 slices x 782 row-chunks of 64; LDS-staged spans, 2-row interleave
  k_spmm<<<8 * 782, 256, 0, stream>>>(Ab, cursor, cnt, csr, Yb, NN);
  k_bnstats<<<SBLK, 256, 0, stream>>>(Yb, part, NN);
  k_bnred<<<16, 256, 0, stream>>>(part, sums1);
  k_bnrc<<<2048, 256, 0, stream>>>(Yb, sums1, g1, be1, Xb, NN * HH / 4);

  // layer 2
  k_gemm<1><<<dim3((NN + 127) / 128, HH / 128), 256, 0, stream>>>(Xb, W2t, nullptr, Ab, NN, HH, HH);
  k_spmm<<<8 * 782, 256, 0, stream>>>(Ab, cursor, cnt, csr, Yb, NN);
  k_bnstats<<<SBLK, 256, 0, stream>>>(Yb, part, NN);
  k_bnred<<<16, 256, 0, stream>>>(part, sums2);
  k_bnrc_pack<<<(M3 * 64) / 256, 256, 0, stream>>>(Yb, sums2, g2, be2, idx, Pb);

  // head: C = Pb @ Wf + bf
  k_gemm<0><<<dim3((M3 + 127) / 128, LL / 128), 256, 0, stream>>>(Pb, Wft, bfb, d_out, M3, HH, LL);
}

// Round 9
// 437.558 us; speedup vs baseline: 1.0694x; 1.0694x over previous
//
#include <hip/hip_runtime.h>
#include <stdint.h>

// Problem constants (fixed by the reference)
#define NN 50000
#define EE 800000
#define FF 256
#define HH 256
#define LL 128
#define SBLK 1024   // bnstats stage-A blocks
#define CSRCAP 1200128  // EE + 8*NN + pad; rows 8-aligned, zero-padded
#define SCAP 512    // staged csr entries per spmm block (4-row spans avg ~64, max ~200)

typedef __bf16 bf16x8 __attribute__((ext_vector_type(8)));
typedef float  f32x4  __attribute__((ext_vector_type(4)));
typedef unsigned int u32x2 __attribute__((ext_vector_type(2)));
typedef unsigned int u32x4 __attribute__((ext_vector_type(4)));

typedef __attribute__((address_space(1))) unsigned int uint_as1;
typedef __attribute__((address_space(3))) unsigned int uint_as3;

__device__ __forceinline__ unsigned short f2bf(float f) {
  union { float f; unsigned int u; } v; v.f = f;
  unsigned int u = v.u;
  u += 0x7FFFu + ((u >> 16) & 1u);   // RTNE (finite inputs only)
  return (unsigned short)(u >> 16);
}

__device__ __forceinline__ float bf2f(unsigned short u) {
  union { unsigned int u; float f; } v;
  v.u = ((unsigned int)u) << 16;
  return v.f;
}

__device__ __forceinline__ f32x4 bf4_to_f32(ushort4 u) {
  f32x4 r;
  r.x = bf2f(u.x); r.y = bf2f(u.y); r.z = bf2f(u.z); r.w = bf2f(u.w);
  return r;
}

__device__ __forceinline__ void gload_lds16(const void* g, void* l) {
  __builtin_amdgcn_global_load_lds((const uint_as1*)g, (uint_as3*)l, 16, 0, 0);
}

// ---------------- fused setup: edge histogram + feature cast + weight transposes ----
// grid: [0,3125) hist | [3125,15625) features | [15625,15665) weight 64x64 tiles
// hist first so its latency-bound atomic waves overlap the streaming casts.
__global__ __launch_bounds__(256) void k_setup(const int* __restrict__ erows,
                                               int* __restrict__ cnt,
                                               const float* __restrict__ features,
                                               unsigned short* __restrict__ Xb,
                                               const float* __restrict__ W1,
                                               unsigned short* __restrict__ W1t,
                                               const float* __restrict__ W2,
                                               unsigned short* __restrict__ W2t,
                                               const float* __restrict__ Wf,
                                               unsigned short* __restrict__ Wft) {
  __shared__ float tl[64 * 65];
  int b = blockIdx.x, t = threadIdx.x;
  if (b < 3125) {
    int i = b * 256 + t;
    if (i < EE) atomicAdd(&cnt[erows[i]], 1);
  } else if (b < 15625) {
    int i = (b - 3125) * 256 + t;  // n4 = 3,200,000 exactly
    f32x4 x = ((const f32x4*)features)[i];
    ushort4 o;
    o.x = f2bf(x.x); o.y = f2bf(x.y); o.z = f2bf(x.z); o.w = f2bf(x.w);
    ((ushort4*)Xb)[i] = o;
  } else {
    int tt = b - 15625;
    const float* in;
    unsigned short* out;
    int Nin, k0, n0;
    if (tt < 16) {
      in = W1; out = W1t; Nin = HH;
      k0 = (tt >> 2) * 64; n0 = (tt & 3) * 64;
    } else if (tt < 32) {
      in = W2; out = W2t; Nin = HH;
      tt -= 16; k0 = (tt >> 2) * 64; n0 = (tt & 3) * 64;
    } else {
      in = Wf; out = Wft; Nin = LL;
      tt -= 32; k0 = (tt >> 1) * 64; n0 = (tt & 1) * 64;
    }
#pragma unroll
    for (int j = 0; j < 16; ++j) {
      int idx = j * 256 + t;
      int r = idx >> 6, c = idx & 63;
      tl[r * 65 + c] = in[(size_t)(k0 + r) * Nin + n0 + c];
    }
    __syncthreads();
#pragma unroll
    for (int j = 0; j < 16; ++j) {
      int idx = j * 256 + t;
      int r = idx >> 6, c = idx & 63;
      out[(size_t)(n0 + r) * HH + k0 + c] = f2bf(tl[c * 65 + r]);
    }
  }
}

// Unordered exclusive allocation, row starts 8-ALIGNED (tail-free spmm oct loops).
// Wave-scan of aligned counts + one global atomic per wave -> any aligned 4-row
// chunk has a CONTIGUOUS ascending csr span (spmm LDS staging relies on this).
// Pad slots stay 0 in csr (pre-zeroed): val=0, harmless.
__global__ __launch_bounds__(256) void k_alloc(const int* __restrict__ cnt,
                                               int* __restrict__ cursor,
                                               int* __restrict__ total, int n) {
  int i = blockIdx.x * 256 + threadIdx.x;
  int lane = threadIdx.x & 63;
  int c = (i < n) ? ((cnt[i] + 7) & ~7) : 0;
  int incl = c;
#pragma unroll
  for (int off = 1; off < 64; off <<= 1) {
    int v = __shfl_up(incl, off, 64);
    if (lane >= off) incl += v;
  }
  int excl = incl - c;
  int wtot = __shfl(incl, 63, 64);
  int base = 0;
  if (lane == 0) base = atomicAdd(total, wtot);
  base = __shfl(base, 0, 64);
  if (i < n) cursor[i] = base + excl;
}

// ---------------- fused layer-1 GEMM + CSR fill ----------------
// 1564 blocks: even = gemm tile (gb = b>>1, 782 tiles of 128x128), odd = fill
// (grid-stride, 4 independent atomic+scatter per thread). Fill's atomic latency
// hides under gemm's MFMA work (separate pipes co-schedule).
// CSR entry packed to 4B: (col << 16) | bf16(val). Row-major C (r8 lesson:
// XCD-sliced layouts lost to the full-row spmm -- slicing removed for good).
__global__ __launch_bounds__(256, 3) void k_l1(const unsigned short* __restrict__ A,
                                               const unsigned short* __restrict__ Bt,
                                               const float* __restrict__ bias,
                                               unsigned short* __restrict__ C,
                                               int M, int K, int Nn,
                                               const int* __restrict__ rows,
                                               const int* __restrict__ cols,
                                               const float* __restrict__ vals,
                                               int* __restrict__ cursor,
                                               unsigned int* __restrict__ csr, int E) {
  __shared__ unsigned short lA[128 * 64];  // 16 KB
  __shared__ unsigned short lB[128 * 64];  // 16 KB
  const int b = blockIdx.x;
  const int tid = threadIdx.x;
  if (b & 1) {
    for (int i = (b >> 1) * 256 + tid; i < E; i += 782 * 256) {
      int p = atomicAdd(&cursor[rows[i]], 1);
      __builtin_nontemporal_store(
          ((unsigned int)cols[i] << 16) | (unsigned int)f2bf(vals[i]), &csr[p]);
    }
    return;
  }
  const int gb = b >> 1;
  const int m0 = (gb % 391) * 128, n0 = (gb / 391) * 128;
  const int wave = tid >> 6, lane = tid & 63;
  const int wm = (wave >> 1) * 64, wn = (wave & 1) * 64;
  const int lhi = lane >> 4, llo = lane & 15;
  const int srow = lane >> 3;
  const int scol = (lane & 7) * 8;
  const unsigned short *pA[4], *pB[4];
#pragma unroll
  for (int j = 0; j < 4; ++j) {
    int base = (wave * 4 + j) * 8 + srow;
    int ar = m0 + base;
    ar = ar < M ? ar : 0;
    pA[j] = A + (size_t)ar * K + scol;
    pB[j] = Bt + (size_t)(n0 + base) * K + scol;
  }
  f32x4 zero = {0.f, 0.f, 0.f, 0.f};
  f32x4 acc[4][4];
#pragma unroll
  for (int i = 0; i < 4; ++i)
#pragma unroll
    for (int j = 0; j < 4; ++j) acc[i][j] = zero;
  for (int k0 = 0; k0 < K; k0 += 64) {
#pragma unroll
    for (int j = 0; j < 4; ++j) {
      gload_lds16(pA[j] + k0, lA + (wave * 4 + j) * 8 * 64);
      gload_lds16(pB[j] + k0, lB + (wave * 4 + j) * 8 * 64);
    }
    __syncthreads();
    bf16x8 af[2][4], bfv[2][4];
#pragma unroll
    for (int ks = 0; ks < 2; ++ks) {
#pragma unroll
      for (int mt = 0; mt < 4; ++mt)
        af[ks][mt] = *(const bf16x8*)(lA + (wm + mt * 16 + llo) * 64 + ks * 32 + lhi * 8);
#pragma unroll
      for (int nt = 0; nt < 4; ++nt)
        bfv[ks][nt] = *(const bf16x8*)(lB + (wn + nt * 16 + llo) * 64 + ks * 32 + lhi * 8);
    }
#pragma unroll
    for (int ks = 0; ks < 2; ++ks)
#pragma unroll
      for (int mt = 0; mt < 4; ++mt)
#pragma unroll
        for (int nt = 0; nt < 4; ++nt)
          acc[mt][nt] = __builtin_amdgcn_mfma_f32_16x16x32_bf16(af[ks][mt], bfv[ks][nt], acc[mt][nt], 0, 0, 0);
    __syncthreads();
  }
#pragma unroll
  for (int nt = 0; nt < 4; ++nt) {
    int cn = n0 + wn + nt * 16 + llo;
    float bv = bias[cn];
#pragma unroll
    for (int mt = 0; mt < 4; ++mt) {
      int cm0 = m0 + wm + mt * 16 + lhi * 4;
#pragma unroll
      for (int r = 0; r < 4; ++r) {
        int cm = cm0 + r;
        if (cm < M) C[(size_t)cm * Nn + cn] = f2bf(acc[mt][nt][r] + bv);
      }
    }
  }
}

// ---------------- SpMM (bf16 in / bf16 out), full-row gather + LDS-staged csr ----
// REVERTED to the round-0 full-row structure (one wave per row, lane = ushort4 ->
// 512B per gather): r0 ran 55.9us, BW-bound at ~3.7 TB/s on the L3-serve path;
// every XCD-sliced variant (r2-r8: 66-149us) lost -- avg degree 16 is too low to
// amortize 8x per-edge decode. Transplanted from the sliced campaign, the two
// proven pieces: (1) LDS-staged csr spans (r7, +25%): block stages its 4 rows'
// contiguous span once (coalesced, parallel), crunch reads wave-uniform LDS
// broadcasts -- no serial global csr chain; (2) 8-aligned rows + zero pads
// (val=0 contributes nothing) -> tail-free 8-wide loop: 8 independent 512B
// gathers + 8 acc chains in flight (r0 had 4). Fallback to global csr for
// spans > SCAP keeps correctness unconditional.
__global__ __launch_bounds__(256) void k_spmm(const unsigned short* __restrict__ X,
                                              const int* __restrict__ endp,
                                              const int* __restrict__ cnt,
                                              const unsigned int* __restrict__ csr,
                                              unsigned short* __restrict__ Y, int n) {
  __shared__ unsigned int lcsr[SCAP];
  const int r0 = blockIdx.x * 4;
  const int tid = threadIdx.x;
  const int wave = tid >> 6, lane = tid & 63;

  // block csr span: rows r0..r0+3 contiguous ascending (k_alloc wave groups)
  const int rlast = (r0 + 3 < n) ? (r0 + 3) : (n - 1);
  const int s0 = endp[r0] - cnt[r0];                 // row r0 start (8-aligned)
  const int clast = cnt[rlast];
  const int send = (endp[rlast] - clast) + ((clast + 7) & ~7);  // aligned end
  const int len0 = send - s0;                        // multiple of 8
  const int len = len0 < SCAP ? len0 : SCAP;
  for (int j = tid * 4; j < len; j += 1024)
    *(u32x4*)(lcsr + j) = __builtin_nontemporal_load((const u32x4*)(csr + s0 + j));
  __syncthreads();

  const int row = r0 + wave;
  if (row >= n) return;
  const int c = cnt[row];
  int q = endp[row] - c;               // row start (8-aligned)
  const int qe = q + ((c + 7) & ~7);   // aligned end (pads are zero entries)

  f32x4 a0 = {0.f, 0.f, 0.f, 0.f}, a1 = a0, a2 = a0, a3 = a0;
  f32x4 a4 = a0, a5 = a0, a6 = a0, a7 = a0;
  auto gat = [&](unsigned int cv) -> ushort4 {
    return ((const ushort4*)(X + ((size_t)(cv >> 16)) * HH))[lane];
  };
  auto oct = [&](u32x4 ca, u32x4 cb) {
    const ushort4 x0 = gat(ca.x), x1 = gat(ca.y), x2 = gat(ca.z), x3 = gat(ca.w);
    const ushort4 x4 = gat(cb.x), x5 = gat(cb.y), x6 = gat(cb.z), x7 = gat(cb.w);
    a0 += bf2f((unsigned short)ca.x) * bf4_to_f32(x0);
    a1 += bf2f((unsigned short)ca.y) * bf4_to_f32(x1);
    a2 += bf2f((unsigned short)ca.z) * bf4_to_f32(x2);
    a3 += bf2f((unsigned short)ca.w) * bf4_to_f32(x3);
    a4 += bf2f((unsigned short)cb.x) * bf4_to_f32(x4);
    a5 += bf2f((unsigned short)cb.y) * bf4_to_f32(x5);
    a6 += bf2f((unsigned short)cb.z) * bf4_to_f32(x6);
    a7 += bf2f((unsigned short)cb.w) * bf4_to_f32(x7);
  };

  if (len0 <= len) {
    const unsigned int* lp = lcsr + (q - s0);
    for (; q < qe; q += 8, lp += 8)
      oct(*(const u32x4*)(lp), *(const u32x4*)(lp + 4));
  } else {
    for (; q < qe; q += 8)
      oct(__builtin_nontemporal_load((const u32x4*)(csr + q)),
          __builtin_nontemporal_load((const u32x4*)(csr + q + 4)));
  }

  const f32x4 a = ((a0 + a1) + (a2 + a3)) + ((a4 + a5) + (a6 + a7));
  ushort4 o;
  o.x = f2bf(a.x); o.y = f2bf(a.y); o.z = f2bf(a.z); o.w = f2bf(a.w);
  ((ushort4*)(Y + (size_t)row * HH))[lane] = o;
}

// ---------------- BatchNorm stats, two-stage (atomic-light) ----------------
__global__ __launch_bounds__(256) void k_bnstats(const unsigned short* __restrict__ X,
                                                 float* __restrict__ part, int n) {
  __shared__ float red[4][64][9];
  const int w = threadIdx.x >> 6, l = threadIdx.x & 63;
  f32x4 s = {0.f, 0.f, 0.f, 0.f}, s2 = {0.f, 0.f, 0.f, 0.f};
  for (int r = blockIdx.x * 4 + w; r < n; r += gridDim.x * 4) {
    f32x4 v = bf4_to_f32(((const ushort4*)(X + (size_t)r * HH))[l]);
    s += v;
    s2 += v * v;
  }
#pragma unroll
  for (int j = 0; j < 4; ++j) { red[w][l][j] = s[j]; red[w][l][4 + j] = s2[j]; }
  __syncthreads();
  if (threadIdx.x < 64) {
    int ll = threadIdx.x;
#pragma unroll
    for (int j = 0; j < 8; ++j) {
      float v = red[0][ll][j] + red[1][ll][j] + red[2][ll][j] + red[3][ll][j];
      int c = ll * 4 + (j & 3);
      part[((j < 4) ? 0 : (SBLK * 256)) + blockIdx.x * 256 + c] = v;
    }
  }
}

// Stage B: 16 blocks = 8 chunks x 2 stats; 128 partials each, 8-deep atomicAdd/col.
__global__ __launch_bounds__(256) void k_bnred(const float* __restrict__ part,
                                               float* __restrict__ sums) {
  int c = threadIdx.x;
  int stat = blockIdx.x >> 3, chunk = blockIdx.x & 7;
  const float* p = part + stat * (SBLK * 256) + chunk * 128 * 256;
  float s0 = 0.f, s1 = 0.f, s2 = 0.f, s3 = 0.f;
  for (int b = 0; b < 128; b += 4) {
    s0 += p[(b + 0) * 256 + c];
    s1 += p[(b + 1) * 256 + c];
    s2 += p[(b + 2) * 256 + c];
    s3 += p[(b + 3) * 256 + c];
  }
  atomicAdd(&sums[stat * HH + c], (s0 + s1) + (s2 + s3));
}

// y = bf16(relu(x*scale + shift)); scale/shift computed per-block from raw sums
__global__ __launch_bounds__(256) void k_bnrc(const unsigned short* __restrict__ X,
                                              const float* __restrict__ sums,
                                              const float* __restrict__ g,
                                              const float* __restrict__ be,
                                              unsigned short* __restrict__ out, int n4) {
  __shared__ float sc[HH], sh[HH];
  int t = threadIdx.x;
  {
    float inv = 1.f / (float)NN;
    float mean = sums[t] * inv;
    float var = sums[HH + t] * inv - mean * mean;
    float s = g[t] * rsqrtf(var + 1e-5f);
    sc[t] = s;
    sh[t] = be[t] - mean * s;
  }
  __syncthreads();
  for (int i = blockIdx.x * 256 + t; i < n4; i += gridDim.x * 256) {
    f32x4 x = bf4_to_f32(((const ushort4*)X)[i]);
    int c0 = (i * 4) & (HH - 1);
    ushort4 o;
    o.x = f2bf(fmaxf(x.x * sc[c0 + 0] + sh[c0 + 0], 0.f));
    o.y = f2bf(fmaxf(x.y * sc[c0 + 1] + sh[c0 + 1], 0.f));
    o.z = f2bf(fmaxf(x.z * sc[c0 + 2] + sh[c0 + 2], 0.f));
    o.w = f2bf(fmaxf(x.w * sc[c0 + 3] + sh[c0 + 3], 0.f));
    ((ushort4*)out)[i] = o;
  }
}

// Layer-2 BN apply, packed for the head: out[r] = bf16(relu(BN(X[idx[r]]))).
__global__ __launch_bounds__(256) void k_bnrc_pack(const unsigned short* __restrict__ X,
                                                   const float* __restrict__ sums,
                                                   const float* __restrict__ g,
                                                   const float* __restrict__ be,
                                                   const int* __restrict__ idx,
                                                   unsigned short* __restrict__ out) {
  __shared__ float sc[HH], sh[HH];
  int t = threadIdx.x;
  {
    float inv = 1.f / (float)NN;
    float mean = sums[t] * inv;
    float var = sums[HH + t] * inv - mean * mean;
    float s = g[t] * rsqrtf(var + 1e-5f);
    sc[t] = s;
    sh[t] = be[t] - mean * s;
  }
  __syncthreads();
  int i = blockIdx.x * 256 + t;
  int orow = i >> 6;           // wave-uniform
  int c0 = (i & 63) * 4;
  int irow = idx[orow];
  f32x4 x = bf4_to_f32(*(const ushort4*)(X + (size_t)irow * HH + c0));
  ushort4 o;
  o.x = f2bf(fmaxf(x.x * sc[c0 + 0] + sh[c0 + 0], 0.f));
  o.y = f2bf(fmaxf(x.y * sc[c0 + 1] + sh[c0 + 1], 0.f));
  o.z = f2bf(fmaxf(x.z * sc[c0 + 2] + sh[c0 + 2], 0.f));
  o.w = f2bf(fmaxf(x.w * sc[c0 + 3] + sh[c0 + 3], 0.f));
  ((ushort4*)out)[i] = o;
}

// ---------------- GEMM: C(MxNn) = A(MxK,bf16) * Bt(NnxK,bf16)^T + bias ----------------
// 128x128 tile, BK=64, 3 blocks/CU. OUTB=1: bf16 out; 0: fp32 out. Row-major.
template <int OUTB>
__global__ __launch_bounds__(256, 3) void k_gemm(const unsigned short* __restrict__ A,
                                                 const unsigned short* __restrict__ Bt,
                                                 const float* __restrict__ bias,
                                                 void* __restrict__ Cv,
                                                 int M, int K, int Nn) {
  __shared__ unsigned short lA[128 * 64];
  __shared__ unsigned short lB[128 * 64];
  const int tid = threadIdx.x;
  const int wave = tid >> 6, lane = tid & 63;
  const int m0 = blockIdx.x * 128, n0 = blockIdx.y * 128;
  const int wm = (wave >> 1) * 64, wn = (wave & 1) * 64;
  const int lhi = lane >> 4, llo = lane & 15;
  const int srow = lane >> 3;
  const int scol = (lane & 7) * 8;
  const unsigned short *pA[4], *pB[4];
#pragma unroll
  for (int j = 0; j < 4; ++j) {
    int base = (wave * 4 + j) * 8 + srow;
    int ar = m0 + base;
    ar = ar < M ? ar : 0;
    pA[j] = A + (size_t)ar * K + scol;
    pB[j] = Bt + (size_t)(n0 + base) * K + scol;
  }
  f32x4 zero = {0.f, 0.f, 0.f, 0.f};
  f32x4 acc[4][4];
#pragma unroll
  for (int i = 0; i < 4; ++i)
#pragma unroll
    for (int j = 0; j < 4; ++j) acc[i][j] = zero;
  for (int k0 = 0; k0 < K; k0 += 64) {
#pragma unroll
    for (int j = 0; j < 4; ++j) {
      gload_lds16(pA[j] + k0, lA + (wave * 4 + j) * 8 * 64);
      gload_lds16(pB[j] + k0, lB + (wave * 4 + j) * 8 * 64);
    }
    __syncthreads();
    bf16x8 af[2][4], bfv[2][4];
#pragma unroll
    for (int ks = 0; ks < 2; ++ks) {
#pragma unroll
      for (int mt = 0; mt < 4; ++mt)
        af[ks][mt] = *(const bf16x8*)(lA + (wm + mt * 16 + llo) * 64 + ks * 32 + lhi * 8);
#pragma unroll
      for (int nt = 0; nt < 4; ++nt)
        bfv[ks][nt] = *(const bf16x8*)(lB + (wn + nt * 16 + llo) * 64 + ks * 32 + lhi * 8);
    }
#pragma unroll
    for (int ks = 0; ks < 2; ++ks)
#pragma unroll
      for (int mt = 0; mt < 4; ++mt)
#pragma unroll
        for (int nt = 0; nt < 4; ++nt)
          acc[mt][nt] = __builtin_amdgcn_mfma_f32_16x16x32_bf16(af[ks][mt], bfv[ks][nt], acc[mt][nt], 0, 0, 0);
    __syncthreads();
  }
#pragma unroll
  for (int nt = 0; nt < 4; ++nt) {
    int cn = n0 + wn + nt * 16 + llo;
    float bv = bias ? bias[cn] : 0.f;
#pragma unroll
    for (int mt = 0; mt < 4; ++mt) {
      int cm0 = m0 + wm + mt * 16 + lhi * 4;
#pragma unroll
      for (int r = 0; r < 4; ++r) {
        int cm = cm0 + r;
        if (cm < M) {
          float v = acc[mt][nt][r] + bv;
          if (OUTB)
            ((unsigned short*)Cv)[(size_t)cm * Nn + cn] = f2bf(v);
          else
            ((float*)Cv)[(size_t)cm * Nn + cn] = v;
        }
      }
    }
  }
}

extern "C" void kernel_launch(void* const* d_in, const int* in_sizes, int n_in,
                              void* d_out, int out_size, void* d_ws, size_t ws_size,
                              hipStream_t stream) {
  const float* features = (const float*)d_in[0];
  const float* edge_vals = (const float*)d_in[1];
  const float* W1 = (const float*)d_in[2];
  const float* db1 = (const float*)d_in[3];
  // d_in[4] = b1  — annihilated by training-mode BN
  const float* g1 = (const float*)d_in[5];
  const float* be1 = (const float*)d_in[6];
  const float* W2 = (const float*)d_in[7];
  // d_in[8] = b2  — annihilated by BN
  const float* g2 = (const float*)d_in[9];
  const float* be2 = (const float*)d_in[10];
  const float* Wf = (const float*)d_in[11];
  const float* bfb = (const float*)d_in[12];
  const int* erows = (const int*)d_in[13];
  const int* ecols = (const int*)d_in[14];
  const int* idx = (const int*)d_in[15];
  const int M3 = in_sizes[15];
  (void)n_in; (void)out_size; (void)ws_size;

  char* ws = (char*)d_ws;
  size_t off = 0;
  auto alloc = [&](size_t bytes) -> void* {
    void* p = (void*)(ws + off);
    off += (bytes + 255) & ~(size_t)255;
    return p;
  };
  unsigned short* Xb = (unsigned short*)alloc((size_t)NN * HH * 2);
  unsigned short* Ab = (unsigned short*)alloc((size_t)NN * HH * 2);
  unsigned short* Yb = (unsigned short*)alloc((size_t)NN * HH * 2);
  unsigned short* Pb = (unsigned short*)alloc((size_t)25000 * HH * 2);
  unsigned short* W1t = (unsigned short*)alloc((size_t)FF * HH * 2);
  unsigned short* W2t = (unsigned short*)alloc((size_t)HH * HH * 2);
  unsigned short* Wft = (unsigned short*)alloc((size_t)HH * LL * 2);
  int* cursor = (int*)alloc((size_t)NN * 4);
  int* cnt = (int*)alloc((size_t)NN * 4);
  unsigned int* csr = (unsigned int*)alloc((size_t)CSRCAP * 4);
  float* part = (float*)alloc((size_t)2 * SBLK * 256 * 4);
  float* stats = (float*)alloc(4 * HH * 4 + 256);
  float* sums1 = stats;
  float* sums2 = stats + 2 * HH;
  int* total = (int*)(stats + 4 * HH);

  hipMemsetAsync(cnt, 0, (size_t)NN * 4, stream);
  hipMemsetAsync(csr, 0, (size_t)CSRCAP * 4, stream);  // zero pads: val=0 entries
  hipMemsetAsync(stats, 0, 4 * HH * 4 + 256, stream);

  // setup: hist + feature cast + weight transposes (one launch, hist first)
  k_setup<<<15665, 256, 0, stream>>>(erows, cnt, features, Xb, W1, W1t, W2, W2t, Wf, Wft);
  k_alloc<<<(NN + 255) / 256, 256, 0, stream>>>(cnt, cursor, total, NN);

  // layer 1: gemm fused with CSR fill (independent work, co-scheduled)
  k_l1<<<1564, 256, 0, stream>>>(Xb, W1t, db1, Ab, NN, FF, HH,
                                 erows, ecols, edge_vals, cursor, csr, EE);
  // after k_l1: cursor[row] == row start + cnt[row]
  // full-row spmm: 4 rows/block, LDS-staged csr span, 8-wide gather ILP
  k_spmm<<<(NN + 3) / 4, 256, 0, stream>>>(Ab, cursor, cnt, csr, Yb, NN);
  k_bnstats<<<SBLK, 256, 0, stream>>>(Yb, part, NN);
  k_bnred<<<16, 256, 0, stream>>>(part, sums1);
  k_bnrc<<<2048, 256, 0, stream>>>(Yb, sums1, g1, be1, Xb, NN * HH / 4);

  // layer 2
  k_gemm<1><<<dim3((NN + 127) / 128, HH / 128), 256, 0, stream>>>(Xb, W2t, nullptr, Ab, NN, HH, HH);
  k_spmm<<<(NN + 3) / 4, 256, 0, stream>>>(Ab, cursor, cnt, csr, Yb, NN);
  k_bnstats<<<SBLK, 256, 0, stream>>>(Yb, part, NN);
  k_bnred<<<16, 256, 0, stream>>>(part, sums2);
  k_bnrc_pack<<<(M3 * 64) / 256, 256, 0, stream>>>(Yb, sums2, g2, be2, idx, Pb);

  // head: C = Pb @ Wf + bf
  k_gemm<0><<<dim3((M3 + 127) / 128, LL / 128), 256, 0, stream>>>(Pb, Wft, bfb, d_out, M3, HH, LL);
}